// Round 2
// baseline (490.751 us; speedup 1.0000x reference)
//
#include <hip/hip_runtime.h>
#include <hip/hip_bf16.h>

#define NN 50000
#define NE 800000
#define HID 128
#define ROWD 68           // x1 LDS pitch in dwords (17 mod 32 spread -> ~2-way banks)
#define APITCH 136        // node-gemm A-tile pitch in bf16 elems
#define N1 (32*128*8)     // W1p shorts
#define N2 (16*128*8)     // W2p shorts
#define NT (NE/64)        // 12500 edge tiles
#define EDGE_GRID 2048    // persistent blocks: 256 CU x 8 (LDS-limited residency)

typedef float f32x4 __attribute__((ext_vector_type(4)));
typedef short s16x8 __attribute__((ext_vector_type(8)));
typedef unsigned int u32;

__device__ __forceinline__ unsigned short f2bf(float x) {   // RNE
    u32 u = __float_as_uint(x);
    u32 r = (u + 0x7FFFu + ((u >> 16) & 1u)) >> 16;
    return (unsigned short)r;
}
__device__ __forceinline__ float silu_f(float v) {          // no IEEE divide
    float e = __expf(-v);
    return v * __builtin_amdgcn_rcpf(1.f + e);
}
__device__ __forceinline__ u32 pack2bf(float lo, float hi) {
    return __builtin_amdgcn_perm(__float_as_uint(hi), __float_as_uint(lo), 0x07060302u);
}
__device__ __forceinline__ u32 fuse_silu_pack(u32 a, u32 b, float ea, float wlo, float whi) {
    float xlo = __uint_as_float(a << 16) + __uint_as_float(b << 16) + ea * wlo;
    float xhi = __uint_as_float(a & 0xFFFF0000u) + __uint_as_float(b & 0xFFFF0000u) + ea * whi;
    return pack2bf(silu_f(xlo), silu_f(xhi));
}

// prep: W1p [32 kblk][128 n][8 kin] bf16; W2p sigma-K bf16 (verified R3-R7);
// and out init = coord * node_mask (replaces memset + lets finalize fold away).
__global__ void prep_kernel(const float* __restrict__ W1, const float* __restrict__ W2,
                            const float* __restrict__ coord, const float* __restrict__ node_mask,
                            unsigned short* __restrict__ W1p, unsigned short* __restrict__ W2p,
                            float* __restrict__ out) {
    int idx = blockIdx.x * blockDim.x + threadIdx.x;
    if (idx < N1) {
        int kblk = idx >> 10;
        int rem  = idx & 1023;
        int n    = rem >> 3;
        int kin  = rem & 7;
        W1p[idx] = f2bf(W1[(kblk * 8 + kin) * HID + n]);
    } else if (idx < N1 + N2) {
        int jj   = idx - N1;
        int kblk = jj >> 10;
        int rem  = jj & 1023;
        int n    = rem >> 3;
        int kin  = rem & 7;
        int p    = kblk * 8 + kin;
        int tt   = p >> 1;
        int srow = 32 * (tt >> 4) + (tt & 15) + 16 * (p & 1);
        W2p[jj] = f2bf(W2[srow * HID + n]);
    } else {
        int i = idx - (N1 + N2);
        if (i < NN) {
            float nm = node_mask[i];
            out[i * 3 + 0] = coord[i * 3 + 0] * nm;
            out[i * 3 + 1] = coord[i * 3 + 1] * nm;
            out[i * 3 + 2] = coord[i * 3 + 2] * nm;
        }
    }
}

// node_gemm: Pa[n] = h[n]@W1a + b1, Pb[n] = h[n]@W1b (sigma-paired bf16, 64 dw/row).
// Exact R4 structure (verified, edge-phase numerics absmax 0.0156).
__global__ __launch_bounds__(256) void node_gemm(const float* __restrict__ h,
                                                 const unsigned short* __restrict__ W1p,
                                                 const float* __restrict__ b1,
                                                 u32* __restrict__ Pa, u32* __restrict__ Pb) {
    __shared__ unsigned short s_a[64 * APITCH];   // 17408 B
    const int tid = threadIdx.x;
    const int m0  = blockIdx.x * 64;

    #pragma unroll
    for (int it = 0; it < 8; ++it) {
        int chunk = it * 256 + tid;
        int r  = chunk >> 5;
        int cc = chunk & 31;
        int row = m0 + r;
        float4 v = {0.f, 0.f, 0.f, 0.f};
        if (row < NN) v = *(const float4*)(h + (size_t)row * HID + cc * 4);
        uint2 pk;
        pk.x = ((u32)f2bf(v.x)) | ((u32)f2bf(v.y) << 16);
        pk.y = ((u32)f2bf(v.z)) | ((u32)f2bf(v.w) << 16);
        *(uint2*)&s_a[r * APITCH + cc * 4] = pk;
    }
    __syncthreads();

    const int lane = tid & 63;
    const int w    = tid >> 6;
    const int q    = lane >> 4;
    const int c16  = lane & 15;
    const int n0   = w * 32 + c16;

    f32x4 accA[4][2], accB[4][2];
    #pragma unroll
    for (int mt = 0; mt < 4; ++mt) {
        accA[mt][0] = f32x4{0.f,0.f,0.f,0.f}; accA[mt][1] = f32x4{0.f,0.f,0.f,0.f};
        accB[mt][0] = f32x4{0.f,0.f,0.f,0.f}; accB[mt][1] = f32x4{0.f,0.f,0.f,0.f};
    }
    #pragma unroll
    for (int ks = 0; ks < 4; ++ks) {
        s16x8 afr[4];
        #pragma unroll
        for (int mt = 0; mt < 4; ++mt)
            afr[mt] = *(const s16x8*)&s_a[(mt * 16 + c16) * APITCH + ks * 32 + q * 8];
        int ka = ks * 4 + q;
        int kb = 16 + ks * 4 + q;
        s16x8 ba0 = *(const s16x8*)(W1p + (size_t)(ka * HID + n0) * 8);
        s16x8 ba1 = *(const s16x8*)(W1p + (size_t)(ka * HID + n0 + 16) * 8);
        s16x8 bb0 = *(const s16x8*)(W1p + (size_t)(kb * HID + n0) * 8);
        s16x8 bb1 = *(const s16x8*)(W1p + (size_t)(kb * HID + n0 + 16) * 8);
        #pragma unroll
        for (int mt = 0; mt < 4; ++mt) {
            accA[mt][0] = __builtin_amdgcn_mfma_f32_16x16x32_bf16(afr[mt], ba0, accA[mt][0], 0, 0, 0);
            accA[mt][1] = __builtin_amdgcn_mfma_f32_16x16x32_bf16(afr[mt], ba1, accA[mt][1], 0, 0, 0);
            accB[mt][0] = __builtin_amdgcn_mfma_f32_16x16x32_bf16(afr[mt], bb0, accB[mt][0], 0, 0, 0);
            accB[mt][1] = __builtin_amdgcn_mfma_f32_16x16x32_bf16(afr[mt], bb1, accB[mt][1], 0, 0, 0);
        }
    }
    float b1lo = b1[n0], b1hi = b1[n0 + 16];
    const int d = w * 16 + c16;
    #pragma unroll
    for (int mt = 0; mt < 4; ++mt) {
        #pragma unroll
        for (int r = 0; r < 4; ++r) {
            int m = mt * 16 + q * 4 + r;     // C/D: col=lane&15, row=quad*4+reg
            int row = m0 + m;
            if (row < NN) {
                Pa[(size_t)row * 64 + d] = pack2bf(accA[mt][0][r] + b1lo, accA[mt][1][r] + b1hi);
                Pb[(size_t)row * 64 + d] = pack2bf(accB[mt][0][r], accB[mt][1][r]);
            }
        }
    }
}

// edge_kernel R9: persistent blocks, grid-stride over 64-edge tiles, 1-deep
// software pipeline. Per tile: next tile's indices prefetched at iteration
// start (breaks index->gather chain); next tile's Pa gathers issued right
// after fuse frees the regs (hide under MFMA), Pb gathers issued after the
// MFMA loop (splits peak VGPR pressure: only 16 staging regs live through
// MFMA). Epilogue's er->node_mask[er] chain issued before the first barrier.
__global__ __launch_bounds__(256, 5) void edge_kernel(
        const u32* __restrict__ Pa, const u32* __restrict__ Pb,
        const int* __restrict__ edge_index,
        const float* __restrict__ coord_diff, const float* __restrict__ edge_attr,
        const float* __restrict__ edge_mask, const float* __restrict__ node_mask,
        const unsigned short* __restrict__ W2p, const float* __restrict__ W1,
        const float* __restrict__ b2, const float* __restrict__ W3,
        float* __restrict__ agg) {
    __shared__ u32   s_x1[64 * ROWD];   // 17408 B
    __shared__ float s_phi[256];        // 1024 B

    const int tid  = threadIdx.x;
    const int lane = tid & 63;
    const int w    = tid >> 6;
    const int q    = lane >> 4;
    const int c16  = lane & 15;
    const int n0   = w * 32 + c16;
    const int c    = tid & 15;          // dword group
    const int rs   = tid >> 4;          // row-sub 0..15

    // fuse constants for dword group c (sigma col map, verified R4)
    const float* W1r = W1 + 256 * HID;
    float w1rlo[4], w1rhi[4];
    #pragma unroll
    for (int i = 0; i < 4; ++i) {
        int dd = c * 4 + i;
        int cl = 32 * (dd >> 4) + (dd & 15);
        w1rlo[i] = W1r[cl];
        w1rhi[i] = W1r[cl + 16];
    }
    const float b2lo = b2[n0], b2hi = b2[n0 + 16];
    const float w3lo = W3[n0], w3hi = W3[n0 + 16];

    const int gstep = gridDim.x;
    int t = blockIdx.x;

    uint4 pa[4], pb[4];
    float eas[4], eas2[4];
    int ci2[4];

    // ---- prologue: issue tile t's gathers ----
    #pragma unroll
    for (int it = 0; it < 4; ++it) {
        int e  = t * 64 + it * 16 + rs;
        int ri = edge_index[e];
        int ciq = edge_index[NE + e];
        eas[it] = edge_attr[e];
        pa[it] = *(const uint4*)(Pa + (size_t)ri * 64 + c * 4);
        pb[it] = *(const uint4*)(Pb + (size_t)ciq * 64 + c * 4);
    }

    while (true) {
        const int e0 = t * 64;
        const int tn = t + gstep;
        const bool hn = (tn < NT);

        // prefetch next tile's indices + edge_attr (independent of this tile)
        int ri2[4];
        if (hn) {
            #pragma unroll
            for (int it = 0; it < 4; ++it) {
                int e = tn * 64 + it * 16 + rs;
                ri2[it]  = edge_index[e];
                ci2[it]  = edge_index[NE + e];
                eas2[it] = edge_attr[e];
            }
        }
        // epilogue prefetch: row index early (feeds node_mask gather below)
        int er = 0;
        if (tid < 64) er = edge_index[e0 + tid];

        // fuse current tile -> s_x1 (first consumer of pa/pb: vmcnt wait here)
        #pragma unroll
        for (int it = 0; it < 4; ++it) {
            int m = it * 16 + rs;
            uint4 o;
            o.x = fuse_silu_pack(pa[it].x, pb[it].x, eas[it], w1rlo[0], w1rhi[0]);
            o.y = fuse_silu_pack(pa[it].y, pb[it].y, eas[it], w1rlo[1], w1rhi[1]);
            o.z = fuse_silu_pack(pa[it].z, pb[it].z, eas[it], w1rlo[2], w1rhi[2]);
            o.w = fuse_silu_pack(pa[it].w, pb[it].w, eas[it], w1rlo[3], w1rhi[3]);
            *(uint4*)&s_x1[m * ROWD + c * 4] = o;
        }
        // pa regs free: issue next tile's Pa gathers (fly through MFMA phase)
        if (hn) {
            #pragma unroll
            for (int it = 0; it < 4; ++it)
                pa[it] = *(const uint4*)(Pa + (size_t)ri2[it] * 64 + c * 4);
        }
        // dependent node_mask gather issued pre-barrier, consumed in epilogue
        float nmv = 0.f;
        if (tid < 64) nmv = node_mask[er];
        __syncthreads();

        // layer 2: [64,128] @ W2p (sigma-K)
        f32x4 acc2[4][2];
        #pragma unroll
        for (int mt = 0; mt < 4; ++mt) {
            acc2[mt][0] = f32x4{0.f,0.f,0.f,0.f};
            acc2[mt][1] = f32x4{0.f,0.f,0.f,0.f};
        }
        #pragma unroll
        for (int ks = 0; ks < 4; ++ks) {
            int kblk = ks * 4 + q;
            s16x8 b0  = *(const s16x8*)(W2p + (size_t)(kblk * HID + n0) * 8);
            s16x8 b1f = *(const s16x8*)(W2p + (size_t)(kblk * HID + n0 + 16) * 8);
            #pragma unroll
            for (int mt = 0; mt < 4; ++mt) {
                s16x8 afr = *(const s16x8*)&s_x1[(mt * 16 + c16) * ROWD + ks * 16 + q * 4];
                acc2[mt][0] = __builtin_amdgcn_mfma_f32_16x16x32_bf16(afr, b0,  acc2[mt][0], 0, 0, 0);
                acc2[mt][1] = __builtin_amdgcn_mfma_f32_16x16x32_bf16(afr, b1f, acc2[mt][1], 0, 0, 0);
            }
        }
        // pb regs free since fuse: issue next tile's Pb gathers (fly through
        // layer3 + epilogue + next iteration's index work)
        if (hn) {
            #pragma unroll
            for (int it = 0; it < 4; ++it)
                pb[it] = *(const uint4*)(Pb + (size_t)ci2[it] * 64 + c * 4);
        }

        // layer 3: phi = sum_n silu(x2+b2)*W3
        #pragma unroll
        for (int mt = 0; mt < 4; ++mt) {
            float pr[4];
            #pragma unroll
            for (int r = 0; r < 4; ++r) {
                float s0 = silu_f(acc2[mt][0][r] + b2lo);
                float s1 = silu_f(acc2[mt][1][r] + b2hi);
                pr[r] = fmaf(s0, w3lo, s1 * w3hi);
            }
            #pragma unroll
            for (int off = 8; off >= 1; off >>= 1) {
                #pragma unroll
                for (int r = 0; r < 4; ++r) pr[r] += __shfl_xor(pr[r], off);
            }
            if (c16 == 0) {
                #pragma unroll
                for (int r = 0; r < 4; ++r)
                    s_phi[(mt * 16 + q * 4 + r) * 4 + w] = pr[r];
            }
        }
        __syncthreads();

        // epilogue: atomics with folded 0.01 * node_mask (er/nmv prefetched)
        if (tid < 64) {
            int e = e0 + tid;
            float phi = s_phi[tid * 4 + 0] + s_phi[tid * 4 + 1]
                      + s_phi[tid * 4 + 2] + s_phi[tid * 4 + 3];
            float scale = phi * edge_mask[e] * 0.01f * nmv;
            atomicAdd(&agg[er * 3 + 0], coord_diff[e * 3 + 0] * scale);
            atomicAdd(&agg[er * 3 + 1], coord_diff[e * 3 + 1] * scale);
            atomicAdd(&agg[er * 3 + 2], coord_diff[e * 3 + 2] * scale);
        }
        // barrier safety across iterations: next fuse writes s_x1 only after
        // this 2nd __syncthreads (all layer2 reads done); next s_phi writes
        // happen after the next 1st barrier, which epilogue threads reach
        // only after their s_phi reads. (Same argument as R4-R8.)
        if (!hn) break;
        t = tn;
        #pragma unroll
        for (int it = 0; it < 4; ++it) eas[it] = eas2[it];
    }
}

extern "C" void kernel_launch(void* const* d_in, const int* in_sizes, int n_in,
                              void* d_out, int out_size, void* d_ws, size_t ws_size,
                              hipStream_t stream) {
    const float* h          = (const float*)d_in[0];
    const float* coord      = (const float*)d_in[1];
    const int*   edge_index = (const int*)d_in[2];
    const float* coord_diff = (const float*)d_in[3];
    // d_in[4] coord_cross: unused
    const float* edge_attr  = (const float*)d_in[5];
    const float* node_mask  = (const float*)d_in[6];
    const float* edge_mask  = (const float*)d_in[7];
    const float* W1         = (const float*)d_in[8];
    const float* b1         = (const float*)d_in[9];
    const float* W2         = (const float*)d_in[10];
    const float* b2         = (const float*)d_in[11];
    const float* W3         = (const float*)d_in[12];
    float* out = (float*)d_out;

    unsigned short* W1p = (unsigned short*)d_ws;
    unsigned short* W2p = W1p + N1;
    u32* Pa = (u32*)(W2p + N2);
    u32* Pb = Pa + (size_t)NN * 64;    // total ~25.7 MB (ws sufficiency proven R4-R7)

    // 3 dispatches: prep (weights + out init) -> node GEMM -> edges
    const int prep_items = N1 + N2 + NN;
    prep_kernel<<<(prep_items + 255) / 256, 256, 0, stream>>>(W1, W2, coord, node_mask,
                                                              W1p, W2p, out);
    node_gemm<<<(NN + 63) / 64, 256, 0, stream>>>(h, W1p, b1, Pa, Pb);
    edge_kernel<<<EDGE_GRID, 256, 0, stream>>>(Pa, Pb, edge_index, coord_diff, edge_attr,
                                               edge_mask, node_mask, W2p, W1, b2, W3, out);
}

// Round 3
// 327.001 us; speedup vs baseline: 1.5008x; 1.5008x over previous
//
#include <hip/hip_runtime.h>
#include <hip/hip_bf16.h>

#define NN 50000
#define NE 800000
#define HID 128
#define ROWD 68           // x1 LDS pitch in dwords (17 mod 32 spread -> ~2-way banks)
#define APITCH 136        // node-gemm A-tile pitch in bf16 elems
#define N1 (32*128*8)     // W1p shorts
#define N2 (16*128*8)     // W2p shorts
#define NB 50000          // sort buckets (= NN)
#define NCH 196           // scan chunks (196*256 = 50176 >= NB)
#define NBP (NCH*256)     // padded bucket count

typedef float f32x4 __attribute__((ext_vector_type(4)));
typedef short s16x8 __attribute__((ext_vector_type(8)));
typedef unsigned int u32;

__device__ __forceinline__ unsigned short f2bf(float x) {   // RNE
    u32 u = __float_as_uint(x);
    u32 r = (u + 0x7FFFu + ((u >> 16) & 1u)) >> 16;
    return (unsigned short)r;
}
__device__ __forceinline__ float silu_f(float v) {          // no IEEE divide
    float e = __expf(-v);
    return v * __builtin_amdgcn_rcpf(1.f + e);
}
__device__ __forceinline__ u32 pack2bf(float lo, float hi) {
    return __builtin_amdgcn_perm(__float_as_uint(hi), __float_as_uint(lo), 0x07060302u);
}
__device__ __forceinline__ u32 fuse_silu_pack(u32 a, u32 b, float ea, float wlo, float whi) {
    float xlo = __uint_as_float(a << 16) + __uint_as_float(b << 16) + ea * wlo;
    float xhi = __uint_as_float(a & 0xFFFF0000u) + __uint_as_float(b & 0xFFFF0000u) + ea * whi;
    return pack2bf(silu_f(xlo), silu_f(xhi));
}

// prep: W1p [32 kblk][128 n][8 kin] bf16; W2p sigma-K bf16 (verified R3-R7);
// out init = coord * node_mask; NEW: zero the sort histogram (NBP ints).
__global__ void prep_kernel(const float* __restrict__ W1, const float* __restrict__ W2,
                            const float* __restrict__ coord, const float* __restrict__ node_mask,
                            unsigned short* __restrict__ W1p, unsigned short* __restrict__ W2p,
                            float* __restrict__ out, int* __restrict__ ofs) {
    int idx = blockIdx.x * blockDim.x + threadIdx.x;
    if (idx < N1) {
        int kblk = idx >> 10;
        int rem  = idx & 1023;
        int n    = rem >> 3;
        int kin  = rem & 7;
        W1p[idx] = f2bf(W1[(kblk * 8 + kin) * HID + n]);
    } else if (idx < N1 + N2) {
        int jj   = idx - N1;
        int kblk = jj >> 10;
        int rem  = jj & 1023;
        int n    = rem >> 3;
        int kin  = rem & 7;
        int p    = kblk * 8 + kin;
        int tt   = p >> 1;
        int srow = 32 * (tt >> 4) + (tt & 15) + 16 * (p & 1);
        W2p[jj] = f2bf(W2[srow * HID + n]);
    } else if (idx < N1 + N2 + NN) {
        int i = idx - (N1 + N2);
        float nm = node_mask[i];
        out[i * 3 + 0] = coord[i * 3 + 0] * nm;
        out[i * 3 + 1] = coord[i * 3 + 1] * nm;
        out[i * 3 + 2] = coord[i * 3 + 2] * nm;
    } else {
        int j = idx - (N1 + N2 + NN);
        if (j < NBP) ofs[j] = 0;
    }
}

// ---- counting sort of edges by row index (ri) ----
__global__ void hist_kernel(const int* __restrict__ edge_index, int* __restrict__ ofs) {
    int e = blockIdx.x * blockDim.x + threadIdx.x;
    if (e < NE) atomicAdd(&ofs[edge_index[e]], 1);
}

// block-local exclusive scan of 256 counts; chunk[b] = block total
__global__ __launch_bounds__(256) void scan1_kernel(int* __restrict__ ofs, int* __restrict__ chunk) {
    __shared__ int s[256];
    int t = threadIdx.x;
    int i = blockIdx.x * 256 + t;
    int v = (i < NB) ? ofs[i] : 0;
    s[t] = v;
    __syncthreads();
    #pragma unroll
    for (int off = 1; off < 256; off <<= 1) {
        int x = (t >= off) ? s[t - off] : 0;
        __syncthreads();
        s[t] += x;
        __syncthreads();
    }
    if (i < NB) ofs[i] = s[t] - v;       // exclusive within chunk
    if (t == 255) chunk[blockIdx.x] = s[255];
}

// exclusive scan of the NCH chunk totals, in place (1 block)
__global__ __launch_bounds__(256) void scan2_kernel(int* __restrict__ chunk) {
    __shared__ int s[256];
    int t = threadIdx.x;
    int v = (t < NCH) ? chunk[t] : 0;
    s[t] = v;
    __syncthreads();
    #pragma unroll
    for (int off = 1; off < 256; off <<= 1) {
        int x = (t >= off) ? s[t - off] : 0;
        __syncthreads();
        s[t] += x;
        __syncthreads();
    }
    if (t < NCH) chunk[t] = s[t] - v;    // exclusive
}

// scatter: pos = chunk_excl[r>>8] + (ofs[r]++ via atomic); perm[pos] = e
__global__ void scatter_kernel(const int* __restrict__ edge_index,
                               int* __restrict__ ofs, const int* __restrict__ chunk,
                               int* __restrict__ perm) {
    int e = blockIdx.x * blockDim.x + threadIdx.x;
    if (e < NE) {
        int r = edge_index[e];
        int pos = chunk[r >> 8] + atomicAdd(&ofs[r], 1);
        perm[pos] = e;
    }
}

// node_gemm: Pa[n] = h[n]@W1a + b1, Pb[n] = h[n]@W1b (sigma-paired bf16, 64 dw/row).
// Exact R4 structure (verified, edge-phase numerics absmax 0.0156).
__global__ __launch_bounds__(256) void node_gemm(const float* __restrict__ h,
                                                 const unsigned short* __restrict__ W1p,
                                                 const float* __restrict__ b1,
                                                 u32* __restrict__ Pa, u32* __restrict__ Pb) {
    __shared__ unsigned short s_a[64 * APITCH];   // 17408 B
    const int tid = threadIdx.x;
    const int m0  = blockIdx.x * 64;

    #pragma unroll
    for (int it = 0; it < 8; ++it) {
        int chunk = it * 256 + tid;
        int r  = chunk >> 5;
        int cc = chunk & 31;
        int row = m0 + r;
        float4 v = {0.f, 0.f, 0.f, 0.f};
        if (row < NN) v = *(const float4*)(h + (size_t)row * HID + cc * 4);
        uint2 pk;
        pk.x = ((u32)f2bf(v.x)) | ((u32)f2bf(v.y) << 16);
        pk.y = ((u32)f2bf(v.z)) | ((u32)f2bf(v.w) << 16);
        *(uint2*)&s_a[r * APITCH + cc * 4] = pk;
    }
    __syncthreads();

    const int lane = tid & 63;
    const int w    = tid >> 6;
    const int q    = lane >> 4;
    const int c16  = lane & 15;
    const int n0   = w * 32 + c16;

    f32x4 accA[4][2], accB[4][2];
    #pragma unroll
    for (int mt = 0; mt < 4; ++mt) {
        accA[mt][0] = f32x4{0.f,0.f,0.f,0.f}; accA[mt][1] = f32x4{0.f,0.f,0.f,0.f};
        accB[mt][0] = f32x4{0.f,0.f,0.f,0.f}; accB[mt][1] = f32x4{0.f,0.f,0.f,0.f};
    }
    #pragma unroll
    for (int ks = 0; ks < 4; ++ks) {
        s16x8 afr[4];
        #pragma unroll
        for (int mt = 0; mt < 4; ++mt)
            afr[mt] = *(const s16x8*)&s_a[(mt * 16 + c16) * APITCH + ks * 32 + q * 8];
        int ka = ks * 4 + q;
        int kb = 16 + ks * 4 + q;
        s16x8 ba0 = *(const s16x8*)(W1p + (size_t)(ka * HID + n0) * 8);
        s16x8 ba1 = *(const s16x8*)(W1p + (size_t)(ka * HID + n0 + 16) * 8);
        s16x8 bb0 = *(const s16x8*)(W1p + (size_t)(kb * HID + n0) * 8);
        s16x8 bb1 = *(const s16x8*)(W1p + (size_t)(kb * HID + n0 + 16) * 8);
        #pragma unroll
        for (int mt = 0; mt < 4; ++mt) {
            accA[mt][0] = __builtin_amdgcn_mfma_f32_16x16x32_bf16(afr[mt], ba0, accA[mt][0], 0, 0, 0);
            accA[mt][1] = __builtin_amdgcn_mfma_f32_16x16x32_bf16(afr[mt], ba1, accA[mt][1], 0, 0, 0);
            accB[mt][0] = __builtin_amdgcn_mfma_f32_16x16x32_bf16(afr[mt], bb0, accB[mt][0], 0, 0, 0);
            accB[mt][1] = __builtin_amdgcn_mfma_f32_16x16x32_bf16(afr[mt], bb1, accB[mt][1], 0, 0, 0);
        }
    }
    float b1lo = b1[n0], b1hi = b1[n0 + 16];
    const int d = w * 16 + c16;
    #pragma unroll
    for (int mt = 0; mt < 4; ++mt) {
        #pragma unroll
        for (int r = 0; r < 4; ++r) {
            int m = mt * 16 + q * 4 + r;     // C/D: col=lane&15, row=quad*4+reg
            int row = m0 + m;
            if (row < NN) {
                Pa[(size_t)row * 64 + d] = pack2bf(accA[mt][0][r] + b1lo, accA[mt][1][r] + b1hi);
                Pb[(size_t)row * 64 + d] = pack2bf(accB[mt][0][r], accB[mt][1][r]);
            }
        }
    }
}

// edge_kernel R10: exact R1 structure (verified, 138 us) + row-sorted edge
// permutation (perm, nullable) + wave-level segmented reduction before atomics.
// Sorted tiles: ~4 distinct rows per 64 edges -> Pa gathers L1/L2-hit, atomics
// ~16x fewer and line-local (kills cross-XCD line bouncing).
__global__ __launch_bounds__(256, 8) void edge_kernel(
        const u32* __restrict__ Pa, const u32* __restrict__ Pb,
        const int* __restrict__ edge_index, const int* __restrict__ perm,
        const float* __restrict__ coord_diff, const float* __restrict__ edge_attr,
        const float* __restrict__ edge_mask, const float* __restrict__ node_mask,
        const unsigned short* __restrict__ W2p, const float* __restrict__ W1,
        const float* __restrict__ b2, const float* __restrict__ W3,
        float* __restrict__ agg) {
    __shared__ u32   s_x1[64 * ROWD];   // 17408 B
    __shared__ float s_phi[256];        // 1024 B

    const int tid  = threadIdx.x;
    const int lane = tid & 63;
    const int w    = tid >> 6;
    const int q    = lane >> 4;
    const int c16  = lane & 15;
    const int n0   = w * 32 + c16;
    const int e0   = blockIdx.x * 64;
    const int c    = tid & 15;          // dword group
    const int rs   = tid >> 4;          // row-sub 0..15

    // fuse constants for dword group c (sigma col map, verified R4)
    const float* W1r = W1 + 256 * HID;
    float w1rlo[4], w1rhi[4];
    #pragma unroll
    for (int i = 0; i < 4; ++i) {
        int dd = c * 4 + i;
        int cl = 32 * (dd >> 4) + (dd & 15);
        w1rlo[i] = W1r[cl];
        w1rhi[i] = W1r[cl + 16];
    }
    const float b2lo = b2[n0], b2hi = b2[n0 + 16];
    const float w3lo = W3[n0], w3hi = W3[n0 + 16];

    // ---- up-front gather for the 64-edge tile: 8 uint4 in flight ----
    uint4 pa[4], pb[4];
    float eas[4];
    #pragma unroll
    for (int it = 0; it < 4; ++it) {
        int e  = e0 + it * 16 + rs;
        int pe = perm ? perm[e] : e;
        int ri = edge_index[pe];
        int ci = edge_index[NE + pe];
        eas[it] = edge_attr[pe];
        pa[it] = *(const uint4*)(Pa + (size_t)ri * 64 + c * 4);
        pb[it] = *(const uint4*)(Pb + (size_t)ci * 64 + c * 4);
    }

    // fuse + write x1 tile (rows 0..63 local)
    #pragma unroll
    for (int it = 0; it < 4; ++it) {
        int m = it * 16 + rs;
        uint4 o;
        o.x = fuse_silu_pack(pa[it].x, pb[it].x, eas[it], w1rlo[0], w1rhi[0]);
        o.y = fuse_silu_pack(pa[it].y, pb[it].y, eas[it], w1rlo[1], w1rhi[1]);
        o.z = fuse_silu_pack(pa[it].z, pb[it].z, eas[it], w1rlo[2], w1rhi[2]);
        o.w = fuse_silu_pack(pa[it].w, pb[it].w, eas[it], w1rlo[3], w1rhi[3]);
        *(uint4*)&s_x1[m * ROWD + c * 4] = o;
    }
    __syncthreads();

    // layer 2: [64,128] @ W2p (sigma-K)
    f32x4 acc2[4][2];
    #pragma unroll
    for (int mt = 0; mt < 4; ++mt) {
        acc2[mt][0] = f32x4{0.f,0.f,0.f,0.f};
        acc2[mt][1] = f32x4{0.f,0.f,0.f,0.f};
    }
    #pragma unroll
    for (int ks = 0; ks < 4; ++ks) {
        int kblk = ks * 4 + q;
        s16x8 b0  = *(const s16x8*)(W2p + (size_t)(kblk * HID + n0) * 8);
        s16x8 b1f = *(const s16x8*)(W2p + (size_t)(kblk * HID + n0 + 16) * 8);
        #pragma unroll
        for (int mt = 0; mt < 4; ++mt) {
            s16x8 afr = *(const s16x8*)&s_x1[(mt * 16 + c16) * ROWD + ks * 16 + q * 4];
            acc2[mt][0] = __builtin_amdgcn_mfma_f32_16x16x32_bf16(afr, b0,  acc2[mt][0], 0, 0, 0);
            acc2[mt][1] = __builtin_amdgcn_mfma_f32_16x16x32_bf16(afr, b1f, acc2[mt][1], 0, 0, 0);
        }
    }

    // layer 3: phi = sum_n silu(x2+b2)*W3
    #pragma unroll
    for (int mt = 0; mt < 4; ++mt) {
        float pr[4];
        #pragma unroll
        for (int r = 0; r < 4; ++r) {
            float s0 = silu_f(acc2[mt][0][r] + b2lo);
            float s1 = silu_f(acc2[mt][1][r] + b2hi);
            pr[r] = fmaf(s0, w3lo, s1 * w3hi);
        }
        #pragma unroll
        for (int off = 8; off >= 1; off >>= 1) {
            #pragma unroll
            for (int r = 0; r < 4; ++r) pr[r] += __shfl_xor(pr[r], off);
        }
        if (c16 == 0) {
            #pragma unroll
            for (int r = 0; r < 4; ++r)
                s_phi[(mt * 16 + q * 4 + r) * 4 + w] = pr[r];
        }
    }
    __syncthreads();

    // epilogue: segmented suffix-sum over sorted rows, then atomics (wave 0)
    if (tid < 64) {
        int e  = e0 + tid;
        int pe = perm ? perm[e] : e;
        float phi = s_phi[tid * 4 + 0] + s_phi[tid * 4 + 1]
                  + s_phi[tid * 4 + 2] + s_phi[tid * 4 + 3];
        int r = edge_index[pe];
        float scale = phi * edge_mask[pe] * 0.01f * node_mask[r];
        float v0 = coord_diff[pe * 3 + 0] * scale;
        float v1 = coord_diff[pe * 3 + 1] * scale;
        float v2 = coord_diff[pe * 3 + 2] * scale;
        // segmented suffix-sum: v_i accumulates contiguous same-r lanes >= i
        #pragma unroll
        for (int off = 1; off < 64; off <<= 1) {
            int   ru = __shfl_down(r,  off);
            float u0 = __shfl_down(v0, off);
            float u1 = __shfl_down(v1, off);
            float u2 = __shfl_down(v2, off);
            if ((tid + off < 64) && (ru == r)) { v0 += u0; v1 += u1; v2 += u2; }
        }
        int rp = __shfl_up(r, 1);
        if (tid == 0 || rp != r) {
            atomicAdd(&agg[r * 3 + 0], v0);
            atomicAdd(&agg[r * 3 + 1], v1);
            atomicAdd(&agg[r * 3 + 2], v2);
        }
    }
}

extern "C" void kernel_launch(void* const* d_in, const int* in_sizes, int n_in,
                              void* d_out, int out_size, void* d_ws, size_t ws_size,
                              hipStream_t stream) {
    const float* h          = (const float*)d_in[0];
    const float* coord      = (const float*)d_in[1];
    const int*   edge_index = (const int*)d_in[2];
    const float* coord_diff = (const float*)d_in[3];
    // d_in[4] coord_cross: unused
    const float* edge_attr  = (const float*)d_in[5];
    const float* node_mask  = (const float*)d_in[6];
    const float* edge_mask  = (const float*)d_in[7];
    const float* W1         = (const float*)d_in[8];
    const float* b1         = (const float*)d_in[9];
    const float* W2         = (const float*)d_in[10];
    const float* b2         = (const float*)d_in[11];
    const float* W3         = (const float*)d_in[12];
    float* out = (float*)d_out;

    // workspace layout
    unsigned short* W1p = (unsigned short*)d_ws;
    unsigned short* W2p = W1p + N1;
    u32* Pa = (u32*)(W2p + N2);
    u32* Pb = Pa + (size_t)NN * 64;
    int* ofs   = (int*)(Pb + (size_t)NN * 64);   // NBP ints (hist -> excl-scan -> cursor)
    int* chunk = ofs + NBP;                       // 256 ints
    int* perm  = chunk + 256;                     // NE ints
    size_t need = (size_t)((char*)(perm + NE) - (char*)d_ws);
    bool do_sort = (ws_size >= need);
    const int* permArg = do_sort ? perm : nullptr;

    const int prep_items = N1 + N2 + NN + NBP;
    prep_kernel<<<(prep_items + 255) / 256, 256, 0, stream>>>(W1, W2, coord, node_mask,
                                                              W1p, W2p, out, ofs);
    if (do_sort) {
        hist_kernel<<<(NE + 255) / 256, 256, 0, stream>>>(edge_index, ofs);
        scan1_kernel<<<NCH, 256, 0, stream>>>(ofs, chunk);
        scan2_kernel<<<1, 256, 0, stream>>>(chunk);
        scatter_kernel<<<(NE + 255) / 256, 256, 0, stream>>>(edge_index, ofs, chunk, perm);
    }
    node_gemm<<<(NN + 63) / 64, 256, 0, stream>>>(h, W1p, b1, Pa, Pb);
    edge_kernel<<<NE / 64, 256, 0, stream>>>(Pa, Pb, edge_index, permArg, coord_diff, edge_attr,
                                             edge_mask, node_mask, W2p, W1, b2, W3, out);
}

// Round 4
// 254.642 us; speedup vs baseline: 1.9272x; 1.2842x over previous
//
#include <hip/hip_runtime.h>
#include <hip/hip_bf16.h>

#define NN 50000
#define NE 800000
#define HID 128
#define ROWD 68           // x1 LDS pitch in dwords (17 mod 32 spread -> ~2-way banks)
#define APITCH 136        // node-gemm A-tile pitch in bf16 elems
#define N1 (32*128*8)     // W1p shorts
#define N2 (16*128*8)     // W2p shorts
#define NT (NE/64)        // 12500 edge tiles
#define EGRID 768         // persistent edge blocks: 256 CU x 3 (LDS-capped)

typedef float f32x4 __attribute__((ext_vector_type(4)));
typedef short s16x8 __attribute__((ext_vector_type(8)));
typedef unsigned int u32;

__device__ __forceinline__ unsigned short f2bf(float x) {   // RNE
    u32 u = __float_as_uint(x);
    u32 r = (u + 0x7FFFu + ((u >> 16) & 1u)) >> 16;
    return (unsigned short)r;
}
__device__ __forceinline__ float silu_f(float v) {          // no IEEE divide
    float e = __expf(-v);
    return v * __builtin_amdgcn_rcpf(1.f + e);
}
__device__ __forceinline__ u32 pack2bf(float lo, float hi) {
    return __builtin_amdgcn_perm(__float_as_uint(hi), __float_as_uint(lo), 0x07060302u);
}
__device__ __forceinline__ u32 fuse_silu_pack(u32 a, u32 b, float ea, float wlo, float whi) {
    float xlo = __uint_as_float(a << 16) + __uint_as_float(b << 16) + ea * wlo;
    float xhi = __uint_as_float(a & 0xFFFF0000u) + __uint_as_float(b & 0xFFFF0000u) + ea * whi;
    return pack2bf(silu_f(xlo), silu_f(xhi));
}
// async gather: per-lane global src, LDS dst = wave-uniform base + lane*16
__device__ __forceinline__ void dma16(const u32* g, u32* l) {
    __builtin_amdgcn_global_load_lds((const __attribute__((address_space(1))) void*)g,
                                     (__attribute__((address_space(3))) void*)l, 16, 0, 0);
}
// barrier without vmcnt drain (DMA stays in flight across it)
__device__ __forceinline__ void bar_lds() {
    asm volatile("s_waitcnt lgkmcnt(0)" ::: "memory");
    __builtin_amdgcn_s_barrier();
}
// 16-lane-row sum via fused DPP rotate-adds (VALU, replaces shfl_xor on DS pipe)
#define ROR_ADD(v, ctrl) (v) += __uint_as_float(__builtin_amdgcn_update_dpp( \
        0, __float_as_uint(v), (ctrl), 0xF, 0xF, false))
#define ROW_SUM16(v) do { ROR_ADD(v,0x128); ROR_ADD(v,0x124); ROR_ADD(v,0x122); ROR_ADD(v,0x121); } while(0)

// prep: W1p [32 kblk][128 n][8 kin] bf16; W2p sigma-K bf16 (verified R3-R7);
// and out init = coord * node_mask (replaces memset + lets finalize fold away).
__global__ void prep_kernel(const float* __restrict__ W1, const float* __restrict__ W2,
                            const float* __restrict__ coord, const float* __restrict__ node_mask,
                            unsigned short* __restrict__ W1p, unsigned short* __restrict__ W2p,
                            float* __restrict__ out) {
    int idx = blockIdx.x * blockDim.x + threadIdx.x;
    if (idx < N1) {
        int kblk = idx >> 10;
        int rem  = idx & 1023;
        int n    = rem >> 3;
        int kin  = rem & 7;
        W1p[idx] = f2bf(W1[(kblk * 8 + kin) * HID + n]);
    } else if (idx < N1 + N2) {
        int jj   = idx - N1;
        int kblk = jj >> 10;
        int rem  = jj & 1023;
        int n    = rem >> 3;
        int kin  = rem & 7;
        int p    = kblk * 8 + kin;
        int tt   = p >> 1;
        int srow = 32 * (tt >> 4) + (tt & 15) + 16 * (p & 1);
        W2p[jj] = f2bf(W2[srow * HID + n]);
    } else {
        int i = idx - (N1 + N2);
        if (i < NN) {
            float nm = node_mask[i];
            out[i * 3 + 0] = coord[i * 3 + 0] * nm;
            out[i * 3 + 1] = coord[i * 3 + 1] * nm;
            out[i * 3 + 2] = coord[i * 3 + 2] * nm;
        }
    }
}

// node_gemm: Pa[n] = h[n]@W1a + b1, Pb[n] = h[n]@W1b (sigma-paired bf16, 64 dw/row).
// Exact R4 structure (verified, edge-phase numerics absmax 0.0156).
__global__ __launch_bounds__(256) void node_gemm(const float* __restrict__ h,
                                                 const unsigned short* __restrict__ W1p,
                                                 const float* __restrict__ b1,
                                                 u32* __restrict__ Pa, u32* __restrict__ Pb) {
    __shared__ unsigned short s_a[64 * APITCH];   // 17408 B
    const int tid = threadIdx.x;
    const int m0  = blockIdx.x * 64;

    #pragma unroll
    for (int it = 0; it < 8; ++it) {
        int chunk = it * 256 + tid;
        int r  = chunk >> 5;
        int cc = chunk & 31;
        int row = m0 + r;
        float4 v = {0.f, 0.f, 0.f, 0.f};
        if (row < NN) v = *(const float4*)(h + (size_t)row * HID + cc * 4);
        uint2 pk;
        pk.x = ((u32)f2bf(v.x)) | ((u32)f2bf(v.y) << 16);
        pk.y = ((u32)f2bf(v.z)) | ((u32)f2bf(v.w) << 16);
        *(uint2*)&s_a[r * APITCH + cc * 4] = pk;
    }
    __syncthreads();

    const int lane = tid & 63;
    const int w    = tid >> 6;
    const int q    = lane >> 4;
    const int c16  = lane & 15;
    const int n0   = w * 32 + c16;

    f32x4 accA[4][2], accB[4][2];
    #pragma unroll
    for (int mt = 0; mt < 4; ++mt) {
        accA[mt][0] = f32x4{0.f,0.f,0.f,0.f}; accA[mt][1] = f32x4{0.f,0.f,0.f,0.f};
        accB[mt][0] = f32x4{0.f,0.f,0.f,0.f}; accB[mt][1] = f32x4{0.f,0.f,0.f,0.f};
    }
    #pragma unroll
    for (int ks = 0; ks < 4; ++ks) {
        s16x8 afr[4];
        #pragma unroll
        for (int mt = 0; mt < 4; ++mt)
            afr[mt] = *(const s16x8*)&s_a[(mt * 16 + c16) * APITCH + ks * 32 + q * 8];
        int ka = ks * 4 + q;
        int kb = 16 + ks * 4 + q;
        s16x8 ba0 = *(const s16x8*)(W1p + (size_t)(ka * HID + n0) * 8);
        s16x8 ba1 = *(const s16x8*)(W1p + (size_t)(ka * HID + n0 + 16) * 8);
        s16x8 bb0 = *(const s16x8*)(W1p + (size_t)(kb * HID + n0) * 8);
        s16x8 bb1 = *(const s16x8*)(W1p + (size_t)(kb * HID + n0 + 16) * 8);
        #pragma unroll
        for (int mt = 0; mt < 4; ++mt) {
            accA[mt][0] = __builtin_amdgcn_mfma_f32_16x16x32_bf16(afr[mt], ba0, accA[mt][0], 0, 0, 0);
            accA[mt][1] = __builtin_amdgcn_mfma_f32_16x16x32_bf16(afr[mt], ba1, accA[mt][1], 0, 0, 0);
            accB[mt][0] = __builtin_amdgcn_mfma_f32_16x16x32_bf16(afr[mt], bb0, accB[mt][0], 0, 0, 0);
            accB[mt][1] = __builtin_amdgcn_mfma_f32_16x16x32_bf16(afr[mt], bb1, accB[mt][1], 0, 0, 0);
        }
    }
    float b1lo = b1[n0], b1hi = b1[n0 + 16];
    const int d = w * 16 + c16;
    #pragma unroll
    for (int mt = 0; mt < 4; ++mt) {
        #pragma unroll
        for (int r = 0; r < 4; ++r) {
            int m = mt * 16 + q * 4 + r;     // C/D: col=lane&15, row=quad*4+reg
            int row = m0 + m;
            if (row < NN) {
                Pa[(size_t)row * 64 + d] = pack2bf(accA[mt][0][r] + b1lo, accA[mt][1][r] + b1hi);
                Pb[(size_t)row * 64 + d] = pack2bf(accB[mt][0][r], accB[mt][1][r]);
            }
        }
    }
}

// edge_kernel R11: persistent 768 blocks, grid-stride, DMA-gather pipeline.
// Next tile's Pa/Pb rows are gathered with global_load_lds (per-lane global
// address, wave-uniform LDS base + lane*16) into raw LDS buffers -> zero VGPR
// staging, no loop-carried vector regs (R2 spill lesson). DMA is issued right
// after fuse frees the raw buffer and stays in flight across BOTH barriers
// (lgkmcnt-only barriers, no vmcnt drain); the loop-top vmcnt(0) lands after
// ~1500 cyc of compute, so gather latency is fully hidden. Wave-locality: wave
// w DMAs and fuse-reads exactly rows {it*16+w*4..+3} -> no extra sync needed.
// W2p fragments preloaded to registers; layer-3 reduce via DPP row_ror adds.
__global__ __launch_bounds__(256, 3) void edge_kernel(
        const u32* __restrict__ Pa, const u32* __restrict__ Pb,
        const int* __restrict__ edge_index,
        const float* __restrict__ coord_diff, const float* __restrict__ edge_attr,
        const float* __restrict__ edge_mask, const float* __restrict__ node_mask,
        const unsigned short* __restrict__ W2p, const float* __restrict__ W1,
        const float* __restrict__ b2, const float* __restrict__ W3,
        float* __restrict__ agg) {
    __shared__ __align__(16) u32 rawA[64 * 64];   // 16384 B: Pa rows of current tile
    __shared__ __align__(16) u32 rawB[64 * 64];   // 16384 B: Pb rows
    __shared__ __align__(16) u32 s_x1[64 * ROWD]; // 17408 B
    __shared__ float s_phi[256];                  // 1024 B   -> 51200 B total, 3 blk/CU

    const int tid  = threadIdx.x;
    const int lane = tid & 63;
    const int w    = tid >> 6;
    const int q    = lane >> 4;
    const int c16  = lane & 15;
    const int n0   = w * 32 + c16;
    const int c    = tid & 15;          // dword group 0..15
    const int rs   = tid >> 4;          // row-sub 0..15 (== w*4 + (lane>>4))

    // fuse constants for dword group c (sigma col map, verified R4)
    const float* W1r = W1 + 256 * HID;
    float w1rlo[4], w1rhi[4];
    #pragma unroll
    for (int i = 0; i < 4; ++i) {
        int dd = c * 4 + i;
        int cl = 32 * (dd >> 4) + (dd & 15);
        w1rlo[i] = W1r[cl];
        w1rhi[i] = W1r[cl + 16];
    }
    const float b2lo = b2[n0], b2hi = b2[n0 + 16];
    const float w3lo = W3[n0], w3hi = W3[n0 + 16];

    // preload W2p fragments (uniform across tiles): 32 VGPRs, kills 8 loads/tile
    s16x8 wb0[4], wb1[4];
    #pragma unroll
    for (int ks = 0; ks < 4; ++ks) {
        int kblk = ks * 4 + q;
        wb0[ks] = *(const s16x8*)(W2p + (size_t)(kblk * HID + n0) * 8);
        wb1[ks] = *(const s16x8*)(W2p + (size_t)(kblk * HID + n0 + 16) * 8);
    }

    int t = blockIdx.x;
    float eas[4];

    // ---- prologue: DMA tile t into raw, load its edge_attr ----
    #pragma unroll
    for (int it = 0; it < 4; ++it) {
        int e  = t * 64 + it * 16 + rs;
        int ri = edge_index[e];
        int ci = edge_index[NE + e];
        eas[it] = edge_attr[e];
        dma16(Pa + (size_t)ri * 64 + c * 4, &rawA[(it * 16 + w * 4) * 64]);
        dma16(Pb + (size_t)ci * 64 + c * 4, &rawB[(it * 16 + w * 4) * 64]);
    }

    while (true) {
        const int e0 = t * 64;
        const int tn = t + EGRID;
        const bool hn = (tn < NT);

        // wait for this tile's DMA (issued >=1 full compute phase ago)
        asm volatile("s_waitcnt vmcnt(0)" ::: "memory");
        __builtin_amdgcn_sched_barrier(0);

        // issue epilogue operands + next tile's indices (hide under fuse)
        int er = 0; float em = 0.f, cd0 = 0.f, cd1 = 0.f, cd2 = 0.f;
        if (tid < 64) {
            int e = e0 + tid;
            er  = edge_index[e];
            em  = edge_mask[e];
            cd0 = coord_diff[e * 3 + 0];
            cd1 = coord_diff[e * 3 + 1];
            cd2 = coord_diff[e * 3 + 2];
        }
        int ri2[4], ci2[4];
        float eas2[4] = {0.f, 0.f, 0.f, 0.f};
        if (hn) {
            #pragma unroll
            for (int it = 0; it < 4; ++it) {
                int e2 = tn * 64 + it * 16 + rs;
                ri2[it]  = edge_index[e2];
                ci2[it]  = edge_index[NE + e2];
                eas2[it] = edge_attr[e2];
            }
        }

        // fuse current tile from raw LDS -> s_x1
        #pragma unroll
        for (int it = 0; it < 4; ++it) {
            int m = it * 16 + rs;
            uint4 a4 = *(const uint4*)&rawA[m * 64 + c * 4];
            uint4 b4 = *(const uint4*)&rawB[m * 64 + c * 4];
            uint4 o;
            o.x = fuse_silu_pack(a4.x, b4.x, eas[it], w1rlo[0], w1rhi[0]);
            o.y = fuse_silu_pack(a4.y, b4.y, eas[it], w1rlo[1], w1rhi[1]);
            o.z = fuse_silu_pack(a4.z, b4.z, eas[it], w1rlo[2], w1rhi[2]);
            o.w = fuse_silu_pack(a4.w, b4.w, eas[it], w1rlo[3], w1rhi[3]);
            *(uint4*)&s_x1[m * ROWD + c * 4] = o;
        }
        // raw is dead for this wave (wave-local rows): DMA next tile now;
        // flies through MFMA + layer3 + epilogue + both barriers.
        if (hn) {
            #pragma unroll
            for (int it = 0; it < 4; ++it) {
                dma16(Pa + (size_t)ri2[it] * 64 + c * 4, &rawA[(it * 16 + w * 4) * 64]);
                dma16(Pb + (size_t)ci2[it] * 64 + c * 4, &rawB[(it * 16 + w * 4) * 64]);
            }
        }
        bar_lds();                        // B1: s_x1 visible (no vmcnt drain)

        float nmv = 0.f;
        if (tid < 64) nmv = node_mask[er];

        // layer 2: [64,128] @ W2p (registers)
        f32x4 acc2[4][2];
        #pragma unroll
        for (int mt = 0; mt < 4; ++mt) {
            acc2[mt][0] = f32x4{0.f,0.f,0.f,0.f};
            acc2[mt][1] = f32x4{0.f,0.f,0.f,0.f};
        }
        #pragma unroll
        for (int ks = 0; ks < 4; ++ks) {
            #pragma unroll
            for (int mt = 0; mt < 4; ++mt) {
                s16x8 afr = *(const s16x8*)&s_x1[(mt * 16 + c16) * ROWD + ks * 16 + q * 4];
                acc2[mt][0] = __builtin_amdgcn_mfma_f32_16x16x32_bf16(afr, wb0[ks], acc2[mt][0], 0, 0, 0);
                acc2[mt][1] = __builtin_amdgcn_mfma_f32_16x16x32_bf16(afr, wb1[ks], acc2[mt][1], 0, 0, 0);
            }
        }

        // layer 3: phi = sum_n silu(x2+b2)*W3; 16-lane reduce via DPP rotates
        #pragma unroll
        for (int mt = 0; mt < 4; ++mt) {
            float pr[4];
            #pragma unroll
            for (int r = 0; r < 4; ++r) {
                float s0 = silu_f(acc2[mt][0][r] + b2lo);
                float s1 = silu_f(acc2[mt][1][r] + b2hi);
                pr[r] = fmaf(s0, w3lo, s1 * w3hi);
            }
            #pragma unroll
            for (int r = 0; r < 4; ++r) ROW_SUM16(pr[r]);
            if (c16 == 0) {
                #pragma unroll
                for (int r = 0; r < 4; ++r)
                    s_phi[(mt * 16 + q * 4 + r) * 4 + w] = pr[r];
            }
        }
        bar_lds();                        // B2: s_phi visible (no vmcnt drain)

        // epilogue: atomics with folded 0.01 * node_mask (all operands prefetched)
        if (tid < 64) {
            float phi = s_phi[tid * 4 + 0] + s_phi[tid * 4 + 1]
                      + s_phi[tid * 4 + 2] + s_phi[tid * 4 + 3];
            float scale = phi * em * 0.01f * nmv;
            atomicAdd(&agg[er * 3 + 0], cd0 * scale);
            atomicAdd(&agg[er * 3 + 1], cd1 * scale);
            atomicAdd(&agg[er * 3 + 2], cd2 * scale);
        }
        // cross-iteration safety: next fuse writes s_x1 only after B2 (all
        // MFMA reads drained at B2's lgkmcnt); next s_phi writes happen after
        // next B1, which epilogue threads reach only after their s_phi reads.
        if (!hn) break;
        t = tn;
        #pragma unroll
        for (int it = 0; it < 4; ++it) eas[it] = eas2[it];
    }
}

extern "C" void kernel_launch(void* const* d_in, const int* in_sizes, int n_in,
                              void* d_out, int out_size, void* d_ws, size_t ws_size,
                              hipStream_t stream) {
    const float* h          = (const float*)d_in[0];
    const float* coord      = (const float*)d_in[1];
    const int*   edge_index = (const int*)d_in[2];
    const float* coord_diff = (const float*)d_in[3];
    // d_in[4] coord_cross: unused
    const float* edge_attr  = (const float*)d_in[5];
    const float* node_mask  = (const float*)d_in[6];
    const float* edge_mask  = (const float*)d_in[7];
    const float* W1         = (const float*)d_in[8];
    const float* b1         = (const float*)d_in[9];
    const float* W2         = (const float*)d_in[10];
    const float* b2         = (const float*)d_in[11];
    const float* W3         = (const float*)d_in[12];
    float* out = (float*)d_out;

    unsigned short* W1p = (unsigned short*)d_ws;
    unsigned short* W2p = W1p + N1;
    u32* Pa = (u32*)(W2p + N2);
    u32* Pb = Pa + (size_t)NN * 64;    // total ~25.7 MB (ws sufficiency proven R4-R7)

    // 3 dispatches: prep (weights + out init) -> node GEMM -> edges
    const int prep_items = N1 + N2 + NN;
    prep_kernel<<<(prep_items + 255) / 256, 256, 0, stream>>>(W1, W2, coord, node_mask,
                                                              W1p, W2p, out);
    node_gemm<<<(NN + 63) / 64, 256, 0, stream>>>(h, W1p, b1, Pa, Pb);
    edge_kernel<<<EGRID, 256, 0, stream>>>(Pa, Pb, edge_index, coord_diff, edge_attr,
                                           edge_mask, node_mask, W2p, W1, b2, W3, out);
}